// Round 4
// baseline (10.580 us; speedup 1.0000x reference)
//
#include <hip/hip_runtime.h>

#define DIM 496  // C(32,2)

__device__ __forceinline__ int pair_off(int p) { return (p * (63 - p)) >> 1; }
__device__ __forceinline__ int pair_idx(int r, int s) { return pair_off(r) + (s - r - 1); }

__global__ __launch_bounds__(256)
void rbs_orbit_kernel(const float* __restrict__ rho,
                      const float* __restrict__ ang,
                      float* __restrict__ out)
{
    __shared__ float sc[16], ss[16];
    __shared__ unsigned char pp[DIM];   // j -> smaller mode p
    __shared__ float v[4][DIM];         // row-pass results

    const int tid = threadIdx.x;
    const int blk = blockIdx.x;   // 0..119 gate-pair orbits, 120..123 identity groups
    const int b   = blockIdx.y;

    // ---- orbit decode (uniform scalar work) ----
    int rows[4];
    int gp = 16, gq = 16;
    if (blk < 120) {
        gp = 0;
        while ((gp + 1) * (30 - gp) / 2 <= blk) ++gp;
        gq = blk - gp * (31 - gp) / 2 + gp + 1;
        const int p0 = 2 * gp, q0 = 2 * gq;
        rows[0] = pair_idx(p0,     q0);
        rows[1] = pair_idx(p0,     q0 + 1);
        rows[2] = pair_idx(p0 + 1, q0);
        rows[3] = pair_idx(p0 + 1, q0 + 1);
    } else {
        const int k = blk - 120;
        #pragma unroll
        for (int t = 0; t < 4; ++t) {
            const int g = 4 * k + t;
            rows[t] = pair_idx(2 * g, 2 * g + 1);
        }
    }

    // ---- issue float4 row loads FIRST (124 lanes x 16B = full row) ----
    const float* base = rho + (size_t)b * DIM * DIM;
    const bool ld = (tid < 124);
    float4 x0, x1, x2, x3;
    if (ld) {
        x0 = reinterpret_cast<const float4*>(base + (size_t)rows[0] * DIM)[tid];
        x1 = reinterpret_cast<const float4*>(base + (size_t)rows[1] * DIM)[tid];
        x2 = reinterpret_cast<const float4*>(base + (size_t)rows[2] * DIM)[tid];
        x3 = reinterpret_cast<const float4*>(base + (size_t)rows[3] * DIM)[tid];
    }

    // ---- LDS tables, overlapped with load latency ----
    if (tid < 16) {
        const float t = (tid < 15) ? ang[tid] : 0.0f;
        float s, c;
        __sincosf(t, &s, &c);
        sc[tid] = c;
        ss[tid] = (tid < 15) ? s : 0.0f;
    }
    if (tid >= 64 && tid < 126) {  // 2 lanes per p fill the p-lookup
        const int l = tid - 64;
        const int p = l >> 1;
        const int off = pair_off(p);
        for (int q = p + 1 + (l & 1); q < 32; q += 2)
            pp[off + q - p - 1] = (unsigned char)p;
    }

    // ---- per-thread M (uniform, overlapped with loads) ----
    float M[4][4];
    if (blk < 120) {
        const float tp = ang[gp];
        const float tq = (gq < 15) ? ang[gq] : 0.0f;
        float sp_, cp, sq_, cq;
        __sincosf(tp, &sp_, &cp);
        __sincosf(tq, &sq_, &cq);
        const float up[2][2] = {{cp, sp_}, {-sp_, cp}};
        const float uq[2][2] = {{cq, sq_}, {-sq_, cq}};
        #pragma unroll
        for (int a = 0; a < 2; ++a)
            #pragma unroll
            for (int bb = 0; bb < 2; ++bb)
                #pragma unroll
                for (int c = 0; c < 2; ++c)
                    #pragma unroll
                    for (int d = 0; d < 2; ++d)
                        M[a * 2 + bb][c * 2 + d] = up[a][c] * uq[bb][d];
    } else {
        #pragma unroll
        for (int a = 0; a < 4; ++a)
            #pragma unroll
            for (int c = 0; c < 4; ++c)
                M[a][c] = (a == c) ? 1.0f : 0.0f;
    }

    // ---- combine loaded rows -> v (float4 writes) ----
    if (ld) {
        #pragma unroll
        for (int r = 0; r < 4; ++r) {
            float4 y;
            y.x = M[r][0] * x0.x + M[r][1] * x1.x + M[r][2] * x2.x + M[r][3] * x3.x;
            y.y = M[r][0] * x0.y + M[r][1] * x1.y + M[r][2] * x2.y + M[r][3] * x3.y;
            y.z = M[r][0] * x0.z + M[r][1] * x1.z + M[r][2] * x2.z + M[r][3] * x3.z;
            y.w = M[r][0] * x0.w + M[r][1] * x1.w + M[r][2] * x2.w + M[r][3] * x3.w;
            reinterpret_cast<float4*>(&v[r][0])[tid] = y;
        }
    }
    __syncthreads();

    // ---- column pass: 4 consecutive j per thread, float4 stores ----
    if (ld) {
        const int j0 = tid * 4;
        // diagonal terms via one b128 read per row
        float4 vd[4];
        #pragma unroll
        for (int r = 0; r < 4; ++r)
            vd[r] = reinterpret_cast<const float4*>(&v[r][0])[tid];

        float res[4][4];
        #pragma unroll
        for (int k = 0; k < 4; ++k) {
            const int j = j0 + k;
            const int p = pp[j];
            const int q = j - pair_off(p) + p + 1;
            const int g1 = p >> 1, g2 = q >> 1;
            const bool id = (g1 == g2);
            const int p1 = p ^ 1, q1 = q ^ 1;
            const int m1 = id ? j : pair_idx(p1, q);
            const int m2 = id ? j : pair_idx(p, q1);
            const int m3 = id ? j : pair_idx(p1, q1);

            const float cp = sc[g1], sp_ = ss[g1];
            const float cq = sc[g2], sq_ = ss[g2];
            const float upP = (p & 1) ? -sp_ : sp_;
            const float uqQ = (q & 1) ? -sq_ : sq_;
            const float c0 = id ? 1.0f : cp * cq;
            const float c1 = id ? 0.0f : upP * cq;
            const float c2 = id ? 0.0f : cp * uqQ;
            const float c3 = id ? 0.0f : upP * uqQ;

            #pragma unroll
            for (int r = 0; r < 4; ++r) {
                const float* vdf = reinterpret_cast<const float*>(&vd[r]);
                res[r][k] = c0 * vdf[k] + c1 * v[r][m1]
                          + c2 * v[r][m2] + c3 * v[r][m3];
            }
        }

        float* obase = out + (size_t)b * DIM * DIM;
        #pragma unroll
        for (int r = 0; r < 4; ++r) {
            float4 y;
            y.x = res[r][0]; y.y = res[r][1]; y.z = res[r][2]; y.w = res[r][3];
            reinterpret_cast<float4*>(obase + (size_t)rows[r] * DIM)[tid] = y;
        }
    }
}

extern "C" void kernel_launch(void* const* d_in, const int* in_sizes, int n_in,
                              void* d_out, int out_size, void* d_ws, size_t ws_size,
                              hipStream_t stream) {
    const float* rho = (const float*)d_in[0];
    const float* ang = (const float*)d_in[1];
    float* out = (float*)d_out;
    dim3 grid(124, 8, 1);
    rbs_orbit_kernel<<<grid, dim3(256, 1, 1), 0, stream>>>(rho, ang, out);
}